// Round 2
// baseline (362.276 us; speedup 1.0000x reference)
//
#include <hip/hip_runtime.h>
#include <math.h>

#define B_    16
#define M_    8
#define T_    250
#define L_    1024
#define NPAIR 28
#define NBT   (B_ * T_)          // 4000

typedef _Float16 half8  __attribute__((ext_vector_type(8)));
typedef _Float16 half2t __attribute__((ext_vector_type(2)));
typedef float    floatx4 __attribute__((ext_vector_type(4)));

__device__ __align__(16) _Float16 g_Btw[64 * 1024];
// A[bt][pair][k] fp16, pair-stride 28 rows of 1024. +64 rows pad so the
// mt=1 MFMA fragment reads (rows 28..31 past the last bt) stay in-bounds.
// Garbage in rows 28..31 only feeds output rows m=12..15, which are never
// stored (pair>=28 check) — NaN-safe because MFMA rows don't mix.
__device__ __align__(16) _Float16 g_A[((size_t)NBT * NPAIR + 64) * 1024];

// np.triu_indices(8, k=1) — used only by the (rare) Nyquist fixup
__constant__ int c_i1[NPAIR] = {0,0,0,0,0,0,0,1,1,1,1,1,1,2,2,2,2,2,3,3,3,3,4,4,4,5,5,6};
__constant__ int c_i2[NPAIR] = {1,2,3,4,5,6,7,2,3,4,5,6,7,3,4,5,6,7,4,5,6,7,5,6,7,6,7,7};

// B[n][k]: k=0 -> DC (1/1024); k=1 -> Nyquist slot ((-1)^n/1024); k=2b -> 2cos/1024, 2b+1 -> -2sin/1024
__global__ void init_btw() {
    int idx = blockIdx.x * 256 + threadIdx.x;
    int n = idx >> 10, k = idx & 1023;
    float v;
    if (k == 0)      v = 1.0f / 1024.0f;
    else if (k == 1) v = (n & 1) ? (-1.0f / 1024.0f) : (1.0f / 1024.0f);
    else {
        int bin = k >> 1, tau = n - 32;
        int r = (tau * bin) & 1023;
        float ang = (float)r * (6.283185307179586f / 1024.0f);
        float s, c; sincosf(ang, &s, &c);
        v = ((k & 1) ? -s : c) * (2.0f / 1024.0f);
    }
    g_Btw[idx] = (_Float16)v;
}

// Bijective XOR swizzle (no padding): bits0-3 ^= bits4-7, bits1-2 ^= bits8-9.
// Conflict-free (4 lanes/16B-group) for strides 512/64/8/1 and the posmap gather.
#define PHI(i) ((i) ^ (((i) >> 4) & 15) ^ ((((i) >> 8) & 3) << 1))

__device__ inline float2 cmul(float2 a, float2 b) {
    return make_float2(fmaf(a.x, b.x, -a.y * b.y), fmaf(a.x, b.y, a.y * b.x));
}
__device__ inline float2 cadd(float2 a, float2 b) { return make_float2(a.x + b.x, a.y + b.y); }
__device__ inline float2 csub(float2 a, float2 b) { return make_float2(a.x - b.x, a.y - b.y); }
__device__ inline float2 cmni(float2 a) { return make_float2(a.y, -a.x); }  // a * (-i)

// DIF 8-point DFT: y_k = sum_r v_r W8^{rk}, in place
__device__ inline void dft8(float2 v[8]) {
    const float rt = 0.70710678118654752440f;
    float2 b0 = cadd(v[0], v[4]), b1 = cadd(v[1], v[5]);
    float2 b2 = cadd(v[2], v[6]), b3 = cadd(v[3], v[7]);
    float2 c0 = csub(v[0], v[4]);
    float2 t1 = csub(v[1], v[5]);
    float2 c1 = make_float2(rt * (t1.x + t1.y), rt * (t1.y - t1.x));   // *W8^1
    float2 c2 = cmni(csub(v[2], v[6]));                                 // *W8^2
    float2 t3 = csub(v[3], v[7]);
    float2 c3 = make_float2(rt * (t3.y - t3.x), -rt * (t3.x + t3.y));  // *W8^3
    float2 f0 = cadd(b0, b2), f1 = cadd(b1, b3);
    float2 g0 = csub(b0, b2), g1 = cmni(csub(b1, b3));
    v[0] = cadd(f0, f1); v[4] = csub(f0, f1);
    v[2] = cadd(g0, g1); v[6] = csub(g0, g1);
    f0 = cadd(c0, c2); f1 = cadd(c1, c3);
    g0 = csub(c0, c2); g1 = cmni(csub(c1, c3));
    v[1] = cadd(f0, f1); v[5] = csub(f0, f1);
    v[3] = cadd(g0, g1); v[7] = csub(g0, g1);
}

__device__ inline void twiddle8(float2 v[8], float2 w1) {
    float2 w = w1;
    v[1] = cmul(v[1], w);
#pragma unroll
    for (int k = 2; k < 8; ++k) { w = cmul(w, w1); v[k] = cmul(v[k], w); }
}

// DIF radices (2,8,8,8): X[k] sits at p(k)
__device__ inline int posmap(int k) {
    return ((k & 1) << 9) | (((k >> 1) & 7) << 6) | (((k >> 4) & 7) << 3) | ((k >> 7) & 7);
}

// ---------------- K1: FFT + PHAT normalize -> g_A (4 barriers, no MFMA) ----------------
__global__ __launch_bounds__(512, 6) void gcc_fft(const float* __restrict__ x) {
    __shared__ float2 s_z[4 * 1024];                                    // 32 KiB only

    const int tid = threadIdx.x;
    const int t = blockIdx.x, b = blockIdx.y;
    const int f = tid & 127, c = tid >> 7;
    float2* Zb = s_z + c * 1024;

    float ws, wc;
    sincosf((float)f * (-6.283185307179586f / 1024.0f), &ws, &wc);
    const float2 w = make_float2(wc, ws);

    // ---- fused global load + radix-2 stage (stride 512) ----
    {
        const float* xa = x + (((size_t)b * M_ + 2 * c) * T_ + t) * L_;
        const float* xb = xa + (size_t)T_ * L_;
        float va[8], vb[8];
#pragma unroll
        for (int j = 0; j < 8; ++j) { va[j] = xa[f + 128 * j]; vb[j] = xb[f + 128 * j]; }
        const float rt = 0.70710678118654752440f;
#pragma unroll
        for (int q = 0; q < 4; ++q) {
            float2 a = make_float2(va[q], vb[q]);
            float2 d = make_float2(va[q + 4], vb[q + 4]);
            float2 tq = cmul(csub(a, d), w);
            float2 r;
            if (q == 0)      r = tq;
            else if (q == 1) r = make_float2(rt * (tq.x + tq.y), rt * (tq.y - tq.x));
            else if (q == 2) r = make_float2(tq.y, -tq.x);
            else             r = make_float2(rt * (tq.y - tq.x), -rt * (tq.x + tq.y));
            Zb[PHI(f + 128 * q)]       = cadd(a, d);
            Zb[PHI(f + 128 * q + 512)] = r;
        }
    }
    __syncthreads();

    // ---- Stage B: radix-8, stride 64 ----
    {
        float2 wl = w;
        if (f & 64) wl = cmul(wl, make_float2(0.92387953251128674f, 0.38268343236508977f));
        const float2 wB = cmul(wl, wl);
        const int base = (f >> 6) * 512 + (f & 63);
        float2 v[8];
#pragma unroll
        for (int r = 0; r < 8; ++r) v[r] = Zb[PHI(base + 64 * r)];
        dft8(v);
        twiddle8(v, wB);
#pragma unroll
        for (int k = 0; k < 8; ++k) Zb[PHI(base + 64 * k)] = v[k];
    }
    __syncthreads();

    // ---- Stage C: radix-8, stride 8 ----
    {
        float s2, c2;
        sincosf((float)(f & 7) * (-6.283185307179586f / 64.0f), &s2, &c2);
        const float2 wC = make_float2(c2, s2);
        const int base = (f >> 3) * 64 + (f & 7);
        float2 v[8];
#pragma unroll
        for (int r = 0; r < 8; ++r) v[r] = Zb[PHI(base + 8 * r)];
        dft8(v);
        twiddle8(v, wC);
#pragma unroll
        for (int k = 0; k < 8; ++k) Zb[PHI(base + 8 * k)] = v[k];
    }
    __syncthreads();

    // ---- Stage D: radix-8, stride 1 (no twiddle) ----
    {
        const int base = f * 8;
        float2 v[8];
#pragma unroll
        for (int r = 0; r < 8; ++r) v[r] = Zb[PHI(base + r)];
        dft8(v);
#pragma unroll
        for (int k = 0; k < 8; ++k) Zb[PHI(base + k)] = v[k];
    }
    __syncthreads();

    // ---- gather + PHAT normalize + store to g_A (no more barriers) ----
    const int bl = tid & 127, pg = tid >> 7;
    const size_t abase = ((size_t)b * T_ + t) * (size_t)(NPAIR * 1024);

#define PAIRG(p_, a_, b_)                                                     \
    {                                                                         \
        float2 X1 = Xs[a_], X2 = Xs[b_];                                      \
        float rr = X1.x * X2.x + X1.y * X2.y;                                 \
        float ri = X1.y * X2.x - X1.x * X2.y;                                 \
        float m2 = rr * rr + ri * ri;                                         \
        float inv = (m2 > 1e-30f) ? rsqrtf(m2) : 0.0f;                        \
        *(half2t*)&g_A[abase + (p_) * 1024 + 2 * beta] =                      \
            (half2t){(_Float16)(rr * inv), (_Float16)(ri * inv)};             \
    }

#pragma unroll 1
    for (int h = 0; h < 4; ++h) {
        const int beta = h * 128 + bl;
        const int pa = posmap(beta);
        const int pb = posmap((1024 - beta) & 1023);
        float2 Xs[8];
#pragma unroll
        for (int cc = 0; cc < 4; ++cc) {
            float2 Aa = s_z[cc * 1024 + PHI(pa)];
            float2 Bb = s_z[cc * 1024 + PHI(pb)];
            Xs[2 * cc]     = make_float2(0.5f * (Aa.x + Bb.x), 0.5f * (Aa.y - Bb.y));
            Xs[2 * cc + 1] = make_float2(0.5f * (Aa.y + Bb.y), 0.5f * (Bb.x - Aa.x));
        }
        if (pg == 0) {
            PAIRG(0, 0, 1) PAIRG(1, 0, 2) PAIRG(2, 0, 3) PAIRG(3, 0, 4)
            PAIRG(4, 0, 5) PAIRG(5, 0, 6) PAIRG(6, 0, 7)
        } else if (pg == 1) {
            PAIRG(7, 1, 2) PAIRG(8, 1, 3) PAIRG(9, 1, 4) PAIRG(10, 1, 5)
            PAIRG(11, 1, 6) PAIRG(12, 1, 7) PAIRG(13, 2, 3)
        } else if (pg == 2) {
            PAIRG(14, 2, 4) PAIRG(15, 2, 5) PAIRG(16, 2, 6) PAIRG(17, 2, 7)
            PAIRG(18, 3, 4) PAIRG(19, 3, 5) PAIRG(20, 3, 6)
        } else {
            PAIRG(21, 3, 7) PAIRG(22, 4, 5) PAIRG(23, 4, 6) PAIRG(24, 4, 7)
            PAIRG(25, 5, 6) PAIRG(26, 5, 7) PAIRG(27, 6, 7)
        }
        if (h == 0 && bl == 0) {               // Nyquist -> hijacked col k=1
            const int pN = 4;                  // PHI(posmap(512)) == 4
#pragma unroll
            for (int pp = 0; pp < 7; ++pp) {
                const int p = pg * 7 + pp;
                float2 Za = s_z[(c_i1[p] >> 1) * 1024 + pN];
                float2 Zc = s_z[(c_i2[p] >> 1) * 1024 + pN];
                float x1 = (c_i1[p] & 1) ? Za.y : Za.x;
                float x2 = (c_i2[p] & 1) ? Zc.y : Zc.x;
                float rr = x1 * x2;
                float inv = (rr * rr > 1e-30f) ? rsqrtf(rr * rr) : 0.0f;
                g_A[abase + p * 1024 + 1] = (_Float16)(rr * inv);
            }
        }
    }
}

// ---------------- K2: one wave per (b,t) GEMM, zero barriers, zero LDS ----------------
__global__ __launch_bounds__(256, 4) void gcc_mm(float* __restrict__ out) {
    const int lane = threadIdx.x & 63, wv = threadIdx.x >> 6;
    const int bt = blockIdx.x * 4 + wv;
    const int l15 = lane & 15, quad = lane >> 4;
    const int b = bt / T_, t = bt - b * T_;

    const _Float16* Ap0 = g_A + ((size_t)bt * NPAIR + l15) * 1024 + quad * 8;
    const _Float16* Ap1 = Ap0 + 16 * 1024;               // rows 28..31: harmless garbage
    const _Float16* Bp  = g_Btw + (size_t)l15 * 1024 + quad * 8;

    floatx4 acc00 = {0,0,0,0}, acc01 = {0,0,0,0}, acc02 = {0,0,0,0}, acc03 = {0,0,0,0};
    floatx4 acc10 = {0,0,0,0}, acc11 = {0,0,0,0}, acc12 = {0,0,0,0}, acc13 = {0,0,0,0};

#pragma unroll 4
    for (int kt = 0; kt < 32; ++kt) {
        half8 a0 = *(const half8*)(Ap0 + kt * 32);
        half8 a1 = *(const half8*)(Ap1 + kt * 32);
        half8 b0 = *(const half8*)(Bp + 0 * 16384 + kt * 32);
        half8 b1 = *(const half8*)(Bp + 1 * 16384 + kt * 32);
        half8 b2 = *(const half8*)(Bp + 2 * 16384 + kt * 32);
        half8 b3 = *(const half8*)(Bp + 3 * 16384 + kt * 32);
        acc00 = __builtin_amdgcn_mfma_f32_16x16x32_f16(a0, b0, acc00, 0, 0, 0);
        acc10 = __builtin_amdgcn_mfma_f32_16x16x32_f16(a1, b0, acc10, 0, 0, 0);
        acc01 = __builtin_amdgcn_mfma_f32_16x16x32_f16(a0, b1, acc01, 0, 0, 0);
        acc11 = __builtin_amdgcn_mfma_f32_16x16x32_f16(a1, b1, acc11, 0, 0, 0);
        acc02 = __builtin_amdgcn_mfma_f32_16x16x32_f16(a0, b2, acc02, 0, 0, 0);
        acc12 = __builtin_amdgcn_mfma_f32_16x16x32_f16(a1, b2, acc12, 0, 0, 0);
        acc03 = __builtin_amdgcn_mfma_f32_16x16x32_f16(a0, b3, acc03, 0, 0, 0);
        acc13 = __builtin_amdgcn_mfma_f32_16x16x32_f16(a1, b3, acc13, 0, 0, 0);
    }

    // Epilogue: C/D layout col=lane&15, row=quad*4+reg; pair = hp*16 + quad*4 + r
    const size_t obase = (((size_t)b * NPAIR) * T_ + t) << 6;
#pragma unroll
    for (int r = 0; r < 4; ++r) {
        int p0 = quad * 4 + r;
        out[obase + ((size_t)p0 * T_ << 6) + 0 * 16 + l15] = acc00[r];
        out[obase + ((size_t)p0 * T_ << 6) + 1 * 16 + l15] = acc01[r];
        out[obase + ((size_t)p0 * T_ << 6) + 2 * 16 + l15] = acc02[r];
        out[obase + ((size_t)p0 * T_ << 6) + 3 * 16 + l15] = acc03[r];
        int p1 = 16 + quad * 4 + r;
        if (p1 < NPAIR) {
            out[obase + ((size_t)p1 * T_ << 6) + 0 * 16 + l15] = acc10[r];
            out[obase + ((size_t)p1 * T_ << 6) + 1 * 16 + l15] = acc11[r];
            out[obase + ((size_t)p1 * T_ << 6) + 2 * 16 + l15] = acc12[r];
            out[obase + ((size_t)p1 * T_ << 6) + 3 * 16 + l15] = acc13[r];
        }
    }
}

extern "C" void kernel_launch(void* const* d_in, const int* in_sizes, int n_in,
                              void* d_out, int out_size, void* d_ws, size_t ws_size,
                              hipStream_t stream) {
    (void)in_sizes; (void)n_in; (void)d_ws; (void)ws_size; (void)out_size;
    hipLaunchKernelGGL(init_btw, dim3(256), dim3(256), 0, stream);
    hipLaunchKernelGGL(gcc_fft, dim3(T_, B_), dim3(512), 0, stream, (const float*)d_in[0]);
    hipLaunchKernelGGL(gcc_mm, dim3(NBT / 4), dim3(256), 0, stream, (float*)d_out);
}